// Round 5
// baseline (453.921 us; speedup 1.0000x reference)
//
#include <hip/hip_runtime.h>
#include <hip/hip_bf16.h>
#include <stdint.h>

#define NB 512
#define NL 128
#define ND 512

typedef __bf16 bf16;
typedef __bf16 bf16x8 __attribute__((ext_vector_type(8)));
typedef float  f32x4  __attribute__((ext_vector_type(4)));

#define GLDS(src, dst) __builtin_amdgcn_global_load_lds( \
    (const __attribute__((address_space(1))) void*)(src), \
    (__attribute__((address_space(3))) void*)(dst), 16, 0, 0)

// ------- K0: att^T -> bf16 (512KB, shared by all mega blocks) -------
__global__ __launch_bounds__(256) void k_attT(const float* __restrict__ att,
                                              bf16* __restrict__ attT) {
    int i = blockIdx.x * 256 + threadIdx.x;   // over 512*512
    int n = i >> 9, k = i & 511;
    attT[i] = (bf16)att[k * 512 + n];
}

// ---- MEGA v5: per-batch block (512 thr), nc-chunked so LDS = ~68KB ->
//      2 blocks/CU (16 waves): one block's gather/stage latency hides under
//      the co-resident block's MFMA. All LDS tiles use the proven XOR-8
//      swizzle (R4's BK=32 layout was an 8-way bank conflict, 6.8M cycles).
//  pre : gather 256 table rows f32 -> bf16 Ab/Bb + block-local sumsq.
//  per nc in 0..3 (128-wide n-chunk of T):
//    A-part: Tchunk = A @ attT[nc]^T   (8 BK=64 steps, stage 32K)
//    write Tchunk -> 32K LDS (swizzled), overlapped with B-slice staging
//    B-part: accS += Tchunk @ B[:,nc]^T (regs persist across nc)
//  then: tanh/S-store/sums/softmax; newA/newB via Ab/Bb re-read (L3-hot).
__global__ __launch_bounds__(512, 4) void k_mega(
        const int* __restrict__ ctx1, const int* __restrict__ ctx2,
        const float* __restrict__ table, const bf16* __restrict__ attT,
        bf16* __restrict__ Ab, bf16* __restrict__ Bb,
        float* __restrict__ Sout, const float* __restrict__ w_pred,
        const float* __restrict__ b_pred, float* __restrict__ logits) {
    const int b = blockIdx.x, row0 = b * NL, tid = threadIdx.x;
    const int lane = tid & 63, w = tid >> 6;
    const int lm = lane & 15, quad = lane >> 4;
    const int wm = (w & 1) * 64;              // m-half (both parts)
    const int wn = (w >> 1) * 32;             // n-quarter within 128-chunk

    // Arena: [0,32K) stage (2x16K tiles; pA/pB in final) |
    //        [32K,64K) Tchunk [2ks][128][64] swz | [64K,+4.25K) smalls
    __shared__ __align__(16) char smem[69888];
    bf16* st0 = (bf16*)smem;                  // [128][64] 16K
    bf16* st1 = (bf16*)(smem + 16384);        // [128][64] 16K
    bf16* Tch = (bf16*)(smem + 32768);        // 32K
    float* pA   = (float*)smem;               // final [8][512]
    float* pB   = (float*)(smem + 16384);     // final [8][512]
    float* red  = (float*)(smem + 65536);     // [16]
    float* red2 = (float*)(smem + 65600);     // [8]
    float* rowb = (float*)(smem + 65664);     // [4][128]
    float* colb = (float*)(smem + 67712);     // [2][128]
    float* wrow = (float*)(smem + 68736);     // [128]
    float* wcol = (float*)(smem + 69248);     // [128]

    // ---------------- pre-phase: gather + convert + sumsq ----------------
    const int r8 = tid >> 6, c8 = tid & 63;   // 8 rows/pass, 64 lanes/row
    float pa = 0.f, pb = 0.f;
    #pragma unroll 4
    for (int j = 0; j < 16; ++j) {
        int l = j * 8 + r8;
        int ia = ctx1[row0 + l], ib = ctx2[row0 + l];
        const float4* ra = (const float4*)table + (size_t)ia * (ND / 4) + c8 * 2;
        const float4* rb = (const float4*)table + (size_t)ib * (ND / 4) + c8 * 2;
        float4 a0 = ra[0], a1 = ra[1];
        float4 b0 = rb[0], b1 = rb[1];
        pa += a0.x*a0.x + a0.y*a0.y + a0.z*a0.z + a0.w*a0.w
            + a1.x*a1.x + a1.y*a1.y + a1.z*a1.z + a1.w*a1.w;
        pb += b0.x*b0.x + b0.y*b0.y + b0.z*b0.z + b0.w*b0.w
            + b1.x*b1.x + b1.y*b1.y + b1.z*b1.z + b1.w*b1.w;
        union { bf16 h[8]; uint4 u; } ua, ub;
        ua.h[0]=(bf16)a0.x; ua.h[1]=(bf16)a0.y; ua.h[2]=(bf16)a0.z; ua.h[3]=(bf16)a0.w;
        ua.h[4]=(bf16)a1.x; ua.h[5]=(bf16)a1.y; ua.h[6]=(bf16)a1.z; ua.h[7]=(bf16)a1.w;
        ub.h[0]=(bf16)b0.x; ub.h[1]=(bf16)b0.y; ub.h[2]=(bf16)b0.z; ub.h[3]=(bf16)b0.w;
        ub.h[4]=(bf16)b1.x; ub.h[5]=(bf16)b1.y; ub.h[6]=(bf16)b1.z; ub.h[7]=(bf16)b1.w;
        *(uint4*)(Ab + (size_t)(row0 + l) * ND + c8 * 8) = ua.u;
        *(uint4*)(Bb + (size_t)(row0 + l) * ND + c8 * 8) = ub.u;
    }
    for (int o = 32; o; o >>= 1) { pa += __shfl_xor(pa, o); pb += __shfl_xor(pb, o); }
    if (lane == 0) { red[w * 2] = pa; red[w * 2 + 1] = pb; }
    __syncthreads();
    float ssA = 0.f, ssB = 0.f;
    #pragma unroll
    for (int i = 0; i < 8; ++i) { ssA += red[i * 2]; ssB += red[i * 2 + 1]; }

    // ---------------- nc-chunked T/S pipeline ----------------
    f32x4 accS[4][2] = {};                    // S[wm..][wn..] persists

    for (int nc = 0; nc < 4; ++nc) {
        const bf16* attN = attT + (size_t)(nc * 128) * ND;
        f32x4 acc1[4][2] = {};                // Tchunk accumulator

        // ---- A-part: Tchunk = A @ attN^T over d=512, BK=64 ----
        for (int t8 = 0; t8 < 8; ++t8) {
            const int k0 = t8 * 64;
            #pragma unroll
            for (int i = 0; i < 2; ++i) {     // stage A->st0, attN->st1
                int s = i * 512 + tid, r = s >> 3, c = (s & 7) ^ (r & 7);
                GLDS(Ab + (size_t)(row0 + r) * ND + k0 + c * 8, st0 + s * 8);
                GLDS(attN + (size_t)r * ND + k0 + c * 8, st1 + s * 8);
            }
            __syncthreads();
            #pragma unroll
            for (int kk = 0; kk < 2; ++kk) {
                bf16x8 af[4], bf2[2];
                const int ca = (kk * 4 + quad) ^ (lm & 7);
                #pragma unroll
                for (int t4 = 0; t4 < 4; ++t4)
                    af[t4] = *(const bf16x8*)&st0[(wm + t4 * 16 + lm) * 64 + ca * 8];
                #pragma unroll
                for (int t2 = 0; t2 < 2; ++t2)
                    bf2[t2] = *(const bf16x8*)&st1[(wn + t2 * 16 + lm) * 64 + ca * 8];
                #pragma unroll
                for (int im = 0; im < 4; ++im)
                    #pragma unroll
                    for (int jn = 0; jn < 2; ++jn)
                        acc1[im][jn] = __builtin_amdgcn_mfma_f32_16x16x32_bf16(
                            af[im], bf2[jn], acc1[im][jn], 0, 0, 0);
            }
            __syncthreads();
        }

        // ---- stage B-slice (both 64-halves) + write Tchunk, one barrier ----
        #pragma unroll
        for (int i = 0; i < 2; ++i) {
            int s = i * 512 + tid, r = s >> 3, c = (s & 7) ^ (r & 7);
            GLDS(Bb + (size_t)(row0 + r) * ND + nc * 128 + c * 8, st0 + s * 8);
            GLDS(Bb + (size_t)(row0 + r) * ND + nc * 128 + 64 + c * 8, st1 + s * 8);
        }
        #pragma unroll
        for (int im = 0; im < 4; ++im)
        #pragma unroll
        for (int jn = 0; jn < 2; ++jn)
        #pragma unroll
        for (int p = 0; p < 4; ++p) {
            int m = wm + im * 16 + quad * 4 + p;   // C/D: col=lane&15, row=quad*4+reg
            int n = wn + jn * 16 + lm;             // 0..127 within chunk
            int ks = n >> 6, c = n & 63;
            int pos = (((c >> 3) ^ (m & 7)) << 3) + (c & 7);
            Tch[ks * 8192 + m * 64 + pos] = (bf16)acc1[im][jn][p];
        }
        __syncthreads();

        // ---- B-part: accS += Tchunk @ Bslice^T (k = 128-wide nc slice) ----
        #pragma unroll
        for (int th = 0; th < 2; ++th) {
            const bf16* Bs_ = th ? st1 : st0;
            const bf16* Tk  = Tch + th * 8192;
            #pragma unroll
            for (int kk = 0; kk < 2; ++kk) {
                bf16x8 af[4], bf2[2];
                const int ca = (kk * 4 + quad) ^ (lm & 7);
                #pragma unroll
                for (int t4 = 0; t4 < 4; ++t4)
                    af[t4] = *(const bf16x8*)&Tk[(wm + t4 * 16 + lm) * 64 + ca * 8];
                #pragma unroll
                for (int t2 = 0; t2 < 2; ++t2)
                    bf2[t2] = *(const bf16x8*)&Bs_[(wn + t2 * 16 + lm) * 64 + ca * 8];
                #pragma unroll
                for (int im = 0; im < 4; ++im)
                    #pragma unroll
                    for (int jn = 0; jn < 2; ++jn)
                        accS[im][jn] = __builtin_amdgcn_mfma_f32_16x16x32_bf16(
                            af[im], bf2[jn], accS[im][jn], 0, 0, 0);
            }
        }
        __syncthreads();
    }

    // ---- S epilogue: tanh + store + row/col sums ----
    const float sc = rsqrtf(ssA * ssB);
    float* __restrict__ Sb = Sout + (size_t)b * NL * NL;
    #pragma unroll
    for (int im = 0; im < 4; ++im)
    #pragma unroll
    for (int jn = 0; jn < 2; ++jn)
    #pragma unroll
    for (int p = 0; p < 4; ++p) {
        float v = tanhf(accS[im][jn][p] * sc);
        accS[im][jn][p] = v;
        int m = wm + im * 16 + quad * 4 + p;
        int n = wn + jn * 16 + lm;
        __builtin_nontemporal_store(v, &Sb[m * NL + n]);
    }
    #pragma unroll
    for (int im = 0; im < 4; ++im)
    #pragma unroll
    for (int p = 0; p < 4; ++p) {
        float r = accS[im][0][p] + accS[im][1][p];
        r += __shfl_xor(r, 1); r += __shfl_xor(r, 2);
        r += __shfl_xor(r, 4); r += __shfl_xor(r, 8);
        if (lm == 0) rowb[(w >> 1) * NL + wm + im * 16 + quad * 4 + p] = r;
    }
    #pragma unroll
    for (int jn = 0; jn < 2; ++jn) {
        float cv = 0.f;
        #pragma unroll
        for (int im = 0; im < 4; ++im)
            #pragma unroll
            for (int p = 0; p < 4; ++p) cv += accS[im][jn][p];
        cv += __shfl_xor(cv, 16); cv += __shfl_xor(cv, 32);
        if (quad == 0) colb[(w & 1) * NL + wn + jn * 16 + lm] = cv;
    }
    __syncthreads();

    // ---- softmax over means (wave0: rows, wave1: cols) ----
    if (tid < 64) {
        float a  = (rowb[tid] + rowb[NL + tid] + rowb[2 * NL + tid] + rowb[3 * NL + tid]) * (1.f / NL);
        float c2 = (rowb[tid + 64] + rowb[NL + tid + 64] + rowb[2 * NL + tid + 64] + rowb[3 * NL + tid + 64]) * (1.f / NL);
        float mx = fmaxf(a, c2);
        for (int o = 32; o; o >>= 1) mx = fmaxf(mx, __shfl_xor(mx, o));
        float e0 = expf(a - mx), e1 = expf(c2 - mx);
        float s = e0 + e1;
        for (int o = 32; o; o >>= 1) s += __shfl_xor(s, o);
        float inv = 1.f / s;
        wrow[tid] = e0 * inv; wrow[tid + 64] = e1 * inv;
    } else if (tid < 128) {
        int q = tid - 64;
        float a  = (colb[q] + colb[NL + q]) * (1.f / NL);
        float c2 = (colb[q + 64] + colb[NL + q + 64]) * (1.f / NL);
        float mx = fmaxf(a, c2);
        for (int o = 32; o; o >>= 1) mx = fmaxf(mx, __shfl_xor(mx, o));
        float e0 = expf(a - mx), e1 = expf(c2 - mx);
        float s = e0 + e1;
        for (int o = 32; o; o >>= 1) s += __shfl_xor(s, o);
        float inv = 1.f / s;
        wcol[q] = e0 * inv; wcol[q + 64] = e1 * inv;
    }
    __syncthreads();

    // ---- weighted sums of A/B rows (stage/Tch dead -> pA/pB) ----
    const int c = tid & 63, g = tid >> 6;
    const bf16* __restrict__ Abase = Ab + (size_t)b * NL * ND;
    const bf16* __restrict__ Bbase = Bb + (size_t)b * NL * ND;
    float aacc[8] = {}, bacc[8] = {};
    for (int l = g; l < NL; l += 8) {
        float wr = wrow[l], wc = wcol[l];
        bf16x8 va = *(const bf16x8*)(Abase + (size_t)l * ND + c * 8);
        bf16x8 vb = *(const bf16x8*)(Bbase + (size_t)l * ND + c * 8);
        #pragma unroll
        for (int j = 0; j < 8; ++j) {
            aacc[j] += wr * (float)va[j];
            bacc[j] += wc * (float)vb[j];
        }
    }
    #pragma unroll
    for (int j = 0; j < 8; ++j) {
        pA[g * ND + c * 8 + j] = aacc[j];
        pB[g * ND + c * 8 + j] = bacc[j];
    }
    __syncthreads();

    if (tid < 64) {
        float dot = 0.f;
        #pragma unroll
        for (int j = 0; j < 8; ++j) {
            int d = tid * 8 + j;
            float na = 0.f, nb = 0.f;
            #pragma unroll
            for (int g2 = 0; g2 < 8; ++g2) {
                na += pA[g2 * ND + d];
                nb += pB[g2 * ND + d];
            }
            dot += na * nb * w_pred[d];
        }
        for (int o = 32; o; o >>= 1) dot += __shfl_xor(dot, o);
        if (tid == 0)
            logits[b] = dot * rsqrtf(ssA) * rsqrtf(ssB) + b_pred[0];
    }
}

extern "C" void kernel_launch(void* const* d_in, const int* in_sizes, int n_in,
                              void* d_out, int out_size, void* d_ws, size_t ws_size,
                              hipStream_t stream) {
    const int*   t1c = (const int*)d_in[2];
    const int*   t2c = (const int*)d_in[3];
    const float* emb = (const float*)d_in[4];
    const float* att = (const float*)d_in[5];
    const float* wp  = (const float*)d_in[6];
    const float* bp  = (const float*)d_in[7];

    float* out    = (float*)d_out;
    float* logits = out;
    float* S      = out + NB;      // outputs: logits(512) then S(512*128*128)

    char* ws = (char*)d_ws;
    bf16*  Ab   = (bf16*)(ws);                              // 67,108,864 B
    bf16*  Bb   = (bf16*)(ws + 67108864);                   // 67,108,864 B
    bf16*  attT = (bf16*)(ws + 134217728);                  //    524,288 B

    k_attT<<<dim3(1024), 256, 0, stream>>>(att, attT);
    k_mega<<<dim3(NB), 512, 0, stream>>>(t1c, t2c, emb, attT, Ab, Bb,
                                         S, wp, bp, logits);
}

// Round 6
// 388.172 us; speedup vs baseline: 1.1694x; 1.1694x over previous
//
#include <hip/hip_runtime.h>
#include <hip/hip_bf16.h>
#include <stdint.h>

#define NB 512
#define NL 128
#define ND 512

typedef __bf16 bf16;
typedef __bf16 bf16x8 __attribute__((ext_vector_type(8)));
typedef float  f32x4  __attribute__((ext_vector_type(4)));

#define GLDS(src, dst) __builtin_amdgcn_global_load_lds( \
    (const __attribute__((address_space(1))) void*)(src), \
    (__attribute__((address_space(3))) void*)(dst), 16, 0, 0)

// ------- K0: att^T -> bf16 (512KB, shared by all mega blocks) -------
__global__ __launch_bounds__(256) void k_attT(const float* __restrict__ att,
                                              bf16* __restrict__ attT) {
    int i = blockIdx.x * 256 + threadIdx.x;   // over 512*512
    int n = i >> 9, k = i & 511;
    attT[i] = (bf16)att[k * 512 + n];
}

// ---- MEGA v6 = R4 structure (single-touch traffic, 176us) + 3 fixes:
//  (1) stage tiles bank-conflict-free: source col-slot pre-swizzled by
//      ((row>>1)&3), read with same XOR (R4's slot=quad was 8-way, 6.8M cyc)
//  (2) counted vmcnt (T4): raw s_barrier + asm vmcnt(5)/(2) instead of
//      __syncthreads' vmcnt(0) drain -> next-step loads fly across barriers
//  (3) s_setprio around MFMA clusters (T5)
//  pre : gather 256 table rows f32 -> bf16 Ab/Bb + block-local sumsq.
//  ph1 : T = A @ attT^T, BK=32 dbuf pipelined, T -> 128KB swizzled LDS.
//  ph2 : S = tanh(T@B^T*sc) AND G = A@diag(w_pred)@B^T (logit = wrow^T G wcol)
__global__ __launch_bounds__(512) void k_mega(
        const int* __restrict__ ctx1, const int* __restrict__ ctx2,
        const float* __restrict__ table, const bf16* __restrict__ attT,
        bf16* __restrict__ Ab, bf16* __restrict__ Bb,
        float* __restrict__ Sout, const float* __restrict__ w_pred,
        const float* __restrict__ b_pred, float* __restrict__ logits) {
    const int b = blockIdx.x, row0 = b * NL, tid = threadIdx.x;
    const int lane = tid & 63, w = tid >> 6;
    const int lm = lane & 15, quad = lane >> 4;
    const int wm  = (w & 1) * 64;             // m-half
    const int wn1 = (w >> 1) * 128;           // ph1 n-chunk (of 512)
    const int wn2 = (w >> 1) * 32;            // ph2 n-chunk (of 128)

    // Arena 160KB: ph1 stages stA dbuf 2x8K @0,8K | stT dbuf 2x32K @16K,48K
    // (end 80K); red[16] @81920; Tls [16][128][32] @0..128K (post-ph1);
    // sB dbuf @128K,136K; sC dbuf @144K,152K (end 160K);
    // S-epilogue smalls alias dead Tls @0.
    __shared__ __align__(16) char smem[163840];
    bf16* stA0 = (bf16*)smem;
    bf16* stA1 = (bf16*)(smem + 8192);
    bf16* stT0 = (bf16*)(smem + 16384);
    bf16* stT1 = (bf16*)(smem + 49152);
    float* red = (float*)(smem + 81920);      // [16]
    bf16* Tls  = (bf16*)smem;                 // 128K
    bf16* sB0  = (bf16*)(smem + 131072);
    bf16* sB1  = (bf16*)(smem + 139264);
    bf16* sC0  = (bf16*)(smem + 147456);
    bf16* sC1  = (bf16*)(smem + 155648);
    float* rowb = (float*)smem;               // [4][128]
    float* colb = (float*)(smem + 2048);      // [2][128]
    float* wrow = (float*)(smem + 3072);      // [128]
    float* wcol = (float*)(smem + 3584);      // [128]
    float* red2 = (float*)(smem + 4096);      // [8]

    // ---------------- pre-phase: gather + convert + sumsq ----------------
    const int r8 = tid >> 6, c8 = tid & 63;
    float pa = 0.f, pb = 0.f;
    #pragma unroll 4
    for (int j = 0; j < 16; ++j) {
        int l = j * 8 + r8;
        int ia = ctx1[row0 + l], ib = ctx2[row0 + l];
        const float4* ra = (const float4*)table + (size_t)ia * (ND / 4) + c8 * 2;
        const float4* rb = (const float4*)table + (size_t)ib * (ND / 4) + c8 * 2;
        float4 a0 = ra[0], a1 = ra[1];
        float4 b0 = rb[0], b1 = rb[1];
        pa += a0.x*a0.x + a0.y*a0.y + a0.z*a0.z + a0.w*a0.w
            + a1.x*a1.x + a1.y*a1.y + a1.z*a1.z + a1.w*a1.w;
        pb += b0.x*b0.x + b0.y*b0.y + b0.z*b0.z + b0.w*b0.w
            + b1.x*b1.x + b1.y*b1.y + b1.z*b1.z + b1.w*b1.w;
        union { bf16 h[8]; uint4 u; } ua, ub;
        ua.h[0]=(bf16)a0.x; ua.h[1]=(bf16)a0.y; ua.h[2]=(bf16)a0.z; ua.h[3]=(bf16)a0.w;
        ua.h[4]=(bf16)a1.x; ua.h[5]=(bf16)a1.y; ua.h[6]=(bf16)a1.z; ua.h[7]=(bf16)a1.w;
        ub.h[0]=(bf16)b0.x; ub.h[1]=(bf16)b0.y; ub.h[2]=(bf16)b0.z; ub.h[3]=(bf16)b0.w;
        ub.h[4]=(bf16)b1.x; ub.h[5]=(bf16)b1.y; ub.h[6]=(bf16)b1.z; ub.h[7]=(bf16)b1.w;
        *(uint4*)(Ab + (size_t)(row0 + l) * ND + c8 * 8) = ua.u;
        *(uint4*)(Bb + (size_t)(row0 + l) * ND + c8 * 8) = ub.u;
    }
    for (int o = 32; o; o >>= 1) { pa += __shfl_xor(pa, o); pb += __shfl_xor(pb, o); }
    if (lane == 0) { red[w * 2] = pa; red[w * 2 + 1] = pb; }
    __syncthreads();                          // drains gather stores too
    float ssA = 0.f, ssB = 0.f;
    #pragma unroll
    for (int i = 0; i < 8; ++i) { ssA += red[i * 2]; ssB += red[i * 2 + 1]; }

    // stage decomposition: thread -> (row r, 16B slot sl), source col-slot
    // pre-swizzled cs = sl ^ ((r>>1)&3); reader XORs the same.
    #define STAGE1(k0, dA, dT) do {                                          \
        { int r_ = tid >> 2, sl_ = tid & 3, cs_ = sl_ ^ ((r_ >> 1) & 3);     \
          GLDS(Ab + (size_t)(row0 + r_) * ND + (k0) + cs_ * 8, (dA) + tid * 8); } \
        _Pragma("unroll")                                                    \
        for (int i_ = 0; i_ < 4; ++i_) {                                     \
            int s_ = i_ * 512 + tid, r_ = s_ >> 2, sl_ = s_ & 3;             \
            int cs_ = sl_ ^ ((r_ >> 1) & 3);                                 \
            GLDS(attT + (size_t)r_ * ND + (k0) + cs_ * 8, (dT) + s_ * 8); }  \
    } while (0)
    #define STAGE2(k0, dB, dC) do {                                          \
        int r_ = tid >> 2, sl_ = tid & 3, cs_ = sl_ ^ ((r_ >> 1) & 3);       \
        GLDS(Bb + (size_t)(row0 + r_) * ND + (k0) + cs_ * 8, (dB) + tid * 8);\
        GLDS(Ab + (size_t)(row0 + r_) * ND + (k0) + cs_ * 8, (dC) + tid * 8);\
    } while (0)

    // ---------------- Phase 1: T = A @ attT^T (BK=32, dbuf) ----------------
    f32x4 acc1[4][8] = {};
    STAGE1(0, stA0, stT0);                    // prologue: step 0 in flight

    for (int t = 0; t < 16; ++t) {
        if (t < 15) {
            STAGE1((t + 1) * 32, (t & 1) ? stA0 : stA1, (t & 1) ? stT0 : stT1);
            asm volatile("s_waitcnt vmcnt(5)" ::: "memory");   // step t's 5 done
        } else {
            STAGE2(0, sB0, sC0);              // prefetch ph2's first tiles
            asm volatile("s_waitcnt vmcnt(2)" ::: "memory");
        }
        __builtin_amdgcn_s_barrier();
        const bf16* A_ = (t & 1) ? stA1 : stA0;
        const bf16* T_ = (t & 1) ? stT1 : stT0;
        bf16x8 af[4], bfm[8];
        #pragma unroll
        for (int t4 = 0; t4 < 4; ++t4) {
            int R = wm + t4 * 16 + lm;
            af[t4] = *(const bf16x8*)&A_[R * 32 + (quad ^ ((R >> 1) & 3)) * 8];
        }
        #pragma unroll
        for (int t8 = 0; t8 < 8; ++t8) {
            int R = wn1 + t8 * 16 + lm;
            bfm[t8] = *(const bf16x8*)&T_[R * 32 + (quad ^ ((R >> 1) & 3)) * 8];
        }
        __builtin_amdgcn_s_setprio(1);
        #pragma unroll
        for (int im = 0; im < 4; ++im)
            #pragma unroll
            for (int jn = 0; jn < 8; ++jn)
                acc1[im][jn] = __builtin_amdgcn_mfma_f32_16x16x32_bf16(
                    af[im], bfm[jn], acc1[im][jn], 0, 0, 0);
        __builtin_amdgcn_s_setprio(0);
        __builtin_amdgcn_s_barrier();         // buffer reusable next iter
    }

    // Phase-1 epilogue: acc1 -> bf16 swizzled Tls (stage bufs dead).
    // Tls[ks][m][pos][e]: ks=n>>5, kq=(n>>3)&3, e=n&7, pos=kq^((m>>2)&3)
    #pragma unroll
    for (int im = 0; im < 4; ++im)
    #pragma unroll
    for (int jn = 0; jn < 8; ++jn)
    #pragma unroll
    for (int p = 0; p < 4; ++p) {
        int m = wm + im * 16 + quad * 4 + p;   // C/D: col=lane&15, row=quad*4+reg
        int n = wn1 + jn * 16 + lm;
        int ks = n >> 5, kq = (n >> 3) & 3, e = n & 7;
        int pos = kq ^ ((m >> 2) & 3);
        Tls[ks * 4096 + m * 32 + pos * 8 + e] = (bf16)acc1[im][jn][p];
    }
    __syncthreads();                          // also drains sB0/sC0 prefetch

    // ------- Phase 2: S = T @ B^T  and  G = A @ diag(w) @ B^T -------
    f32x4 acc2[4][2] = {}, accG[4][2] = {};

    for (int t = 0; t < 16; ++t) {
        if (t < 15) {
            STAGE2((t + 1) * 32, (t & 1) ? sB0 : sB1, (t & 1) ? sC0 : sC1);
            asm volatile("s_waitcnt vmcnt(2)" ::: "memory");
        } else {
            asm volatile("s_waitcnt vmcnt(0)" ::: "memory");
        }
        __builtin_amdgcn_s_barrier();
        const bf16* B_ = (t & 1) ? sB1 : sB0;
        const bf16* C_ = (t & 1) ? sC1 : sC0;
        float4 w0 = *(const float4*)(w_pred + t * 32 + quad * 8);
        float4 w1 = *(const float4*)(w_pred + t * 32 + quad * 8 + 4);
        float wv[8] = {w0.x, w0.y, w0.z, w0.w, w1.x, w1.y, w1.z, w1.w};
        bf16x8 af[4], af2[4], bf2[2], bfw[2];
        #pragma unroll
        for (int t4 = 0; t4 < 4; ++t4) {
            int R = wm + t4 * 16 + lm;
            af[t4]  = *(const bf16x8*)&Tls[t * 4096 + R * 32 + (quad ^ ((R >> 2) & 3)) * 8];
            af2[t4] = *(const bf16x8*)&C_[R * 32 + (quad ^ ((R >> 1) & 3)) * 8];
        }
        #pragma unroll
        for (int t2 = 0; t2 < 2; ++t2) {
            int R = wn2 + t2 * 16 + lm;
            bf2[t2] = *(const bf16x8*)&B_[R * 32 + (quad ^ ((R >> 1) & 3)) * 8];
            #pragma unroll
            for (int j = 0; j < 8; ++j)
                bfw[t2][j] = (bf16)((float)bf2[t2][j] * wv[j]);
        }
        __builtin_amdgcn_s_setprio(1);
        #pragma unroll
        for (int im = 0; im < 4; ++im)
            #pragma unroll
            for (int jn = 0; jn < 2; ++jn) {
                acc2[im][jn] = __builtin_amdgcn_mfma_f32_16x16x32_bf16(
                    af[im], bf2[jn], acc2[im][jn], 0, 0, 0);
                accG[im][jn] = __builtin_amdgcn_mfma_f32_16x16x32_bf16(
                    af2[im], bfw[jn], accG[im][jn], 0, 0, 0);
            }
        __builtin_amdgcn_s_setprio(0);
        __builtin_amdgcn_s_barrier();
    }

    // ---- S epilogue: tanh + store + row/col sums (Tls dead -> smalls) ----
    const float sc = rsqrtf(ssA * ssB);
    float* __restrict__ Sb = Sout + (size_t)b * NL * NL;
    #pragma unroll
    for (int im = 0; im < 4; ++im)
    #pragma unroll
    for (int jn = 0; jn < 2; ++jn)
    #pragma unroll
    for (int p = 0; p < 4; ++p) {
        float v = tanhf(acc2[im][jn][p] * sc);
        acc2[im][jn][p] = v;
        int m = wm + im * 16 + quad * 4 + p;
        int n = wn2 + jn * 16 + lm;
        __builtin_nontemporal_store(v, &Sb[m * NL + n]);
    }
    #pragma unroll
    for (int im = 0; im < 4; ++im)
    #pragma unroll
    for (int p = 0; p < 4; ++p) {
        float r = acc2[im][0][p] + acc2[im][1][p];
        r += __shfl_xor(r, 1); r += __shfl_xor(r, 2);
        r += __shfl_xor(r, 4); r += __shfl_xor(r, 8);
        if (lm == 0) rowb[(w >> 1) * NL + wm + im * 16 + quad * 4 + p] = r;
    }
    #pragma unroll
    for (int jn = 0; jn < 2; ++jn) {
        float cv = 0.f;
        #pragma unroll
        for (int im = 0; im < 4; ++im)
            #pragma unroll
            for (int p = 0; p < 4; ++p) cv += acc2[im][jn][p];
        cv += __shfl_xor(cv, 16); cv += __shfl_xor(cv, 32);
        if (quad == 0) colb[(w & 1) * NL + wn2 + jn * 16 + lm] = cv;
    }
    __syncthreads();

    // ---- softmax over means (wave0: rows, wave1: cols) ----
    if (tid < 64) {
        float a  = (rowb[tid] + rowb[NL + tid] + rowb[2 * NL + tid] + rowb[3 * NL + tid]) * (1.f / NL);
        float c2 = (rowb[tid + 64] + rowb[NL + tid + 64] + rowb[2 * NL + tid + 64] + rowb[3 * NL + tid + 64]) * (1.f / NL);
        float mx = fmaxf(a, c2);
        for (int o = 32; o; o >>= 1) mx = fmaxf(mx, __shfl_xor(mx, o));
        float e0 = expf(a - mx), e1 = expf(c2 - mx);
        float s = e0 + e1;
        for (int o = 32; o; o >>= 1) s += __shfl_xor(s, o);
        float inv = 1.f / s;
        wrow[tid] = e0 * inv; wrow[tid + 64] = e1 * inv;
    } else if (tid < 128) {
        int q = tid - 64;
        float a  = (colb[q] + colb[NL + q]) * (1.f / NL);
        float c2 = (colb[q + 64] + colb[NL + q + 64]) * (1.f / NL);
        float mx = fmaxf(a, c2);
        for (int o = 32; o; o >>= 1) mx = fmaxf(mx, __shfl_xor(mx, o));
        float e0 = expf(a - mx), e1 = expf(c2 - mx);
        float s = e0 + e1;
        for (int o = 32; o; o >>= 1) s += __shfl_xor(s, o);
        float inv = 1.f / s;
        wcol[q] = e0 * inv; wcol[q + 64] = e1 * inv;
    }
    __syncthreads();

    // ---- logit = sc * wrow^T G wcol ----
    float wc0 = wcol[wn2 + lm], wc1 = wcol[wn2 + 16 + lm];
    float g = 0.f;
    #pragma unroll
    for (int im = 0; im < 4; ++im)
    #pragma unroll
    for (int p = 0; p < 4; ++p) {
        float wr = wrow[wm + im * 16 + quad * 4 + p];
        g += wr * (wc0 * accG[im][0][p] + wc1 * accG[im][1][p]);
    }
    for (int o = 32; o; o >>= 1) g += __shfl_xor(g, o);
    if (lane == 0) red2[w] = g;
    __syncthreads();
    if (tid == 0) {
        float tot = 0.f;
        #pragma unroll
        for (int i = 0; i < 8; ++i) tot += red2[i];
        logits[b] = tot * sc + b_pred[0];
    }
}

extern "C" void kernel_launch(void* const* d_in, const int* in_sizes, int n_in,
                              void* d_out, int out_size, void* d_ws, size_t ws_size,
                              hipStream_t stream) {
    const int*   t1c = (const int*)d_in[2];
    const int*   t2c = (const int*)d_in[3];
    const float* emb = (const float*)d_in[4];
    const float* att = (const float*)d_in[5];
    const float* wp  = (const float*)d_in[6];
    const float* bp  = (const float*)d_in[7];

    float* out    = (float*)d_out;
    float* logits = out;
    float* S      = out + NB;      // outputs: logits(512) then S(512*128*128)

    char* ws = (char*)d_ws;
    bf16*  Ab   = (bf16*)(ws);                              // 67,108,864 B
    bf16*  Bb   = (bf16*)(ws + 67108864);                   // 67,108,864 B
    bf16*  attT = (bf16*)(ws + 134217728);                  //    524,288 B

    k_attT<<<dim3(1024), 256, 0, stream>>>(att, attT);
    k_mega<<<dim3(NB), 512, 0, stream>>>(t1c, t2c, emb, attT, Ab, Bb,
                                         S, wp, bp, logits);
}